// Round 21
// baseline (205.718 us; speedup 1.0000x reference)
//
#include <hip/hip_runtime.h>
#include <hip/hip_bf16.h>

typedef unsigned short u16;
typedef float f32x4 __attribute__((ext_vector_type(4)));
typedef float f32x16 __attribute__((ext_vector_type(16)));
typedef __bf16 bf16x4 __attribute__((ext_vector_type(4)));
typedef __bf16 bf16x8 __attribute__((ext_vector_type(8)));
typedef _Float16 half4 __attribute__((ext_vector_type(4)));
typedef _Float16 half8 __attribute__((ext_vector_type(8)));
typedef u16 u16x4 __attribute__((ext_vector_type(4)));
typedef u16 u16x8 __attribute__((ext_vector_type(8)));

#define NPIX 4096
#define CDIM 512
#define LOG2E 1.4426950408889634f

static __device__ __forceinline__ u16 f2bf(float f) {
  return __builtin_bit_cast(u16, (__bf16)f);
}
static __device__ __forceinline__ float bf2f(u16 u) {
  unsigned int v = ((unsigned int)u) << 16;
  return __builtin_bit_cast(float, v);
}
static __device__ __forceinline__ u16 f2h(float f) {
  return __builtin_bit_cast(u16, (_Float16)f);
}
static __device__ __forceinline__ f32x16 zero16() {
  f32x16 z;
#pragma unroll
  for (int i = 0; i < 16; ++i) z[i] = 0.0f;
  return z;
}
static __device__ __forceinline__ f32x16 mfma_bf(bf16x8 a, bf16x8 b, f32x16 c) {
  return __builtin_amdgcn_mfma_f32_32x32x16_bf16(a, b, c, 0, 0, 0);
}
static __device__ __forceinline__ f32x16 mfma_h32(half8 a, half8 b, f32x16 c) {
  return __builtin_amdgcn_mfma_f32_32x32x16_f16(a, b, c, 0, 0, 0);
}
static __device__ __forceinline__ half8 h8(half4 a, half4 b) {
  half8 r;
#pragma unroll
  for (int i = 0; i < 4; ++i) { r[i] = a[i]; r[4 + i] = b[i]; }
  return r;
}
static __device__ __forceinline__ bf16x8 b8(bf16x4 a, bf16x4 b) {
  bf16x8 r;
#pragma unroll
  for (int i = 0; i < 4; ++i) { r[i] = a[i]; r[4 + i] = b[i]; }
  return r;
}

// ---------------------------------------------------------------------------
// Kernel 1: fused QKV projection, REBUILT to fit the 64-VGPR envelope.
// R20 post-mortem: 640-thr blocks get 64 VGPRs (R7-R9 ledger) but the old
// acc[2][2] was 64 regs alone -> proj has been spilling accumulators since
// R1 (50 µs for 10.7 GF, immune to micro-fixes). New shape: wave owns
// 32 rows x 32 n (acc = ONE f32x16 = 16 regs; total ~50). Grid (128 nt,
// 4 b, 2 row-halves of 320). Whole x-tile [512k x 32n] staged once as
// fp16 (stride 524 u16 -> 2-way LDS reads), then a BARRIER-FREE 32-step
// MFMA loop (compiler pipelines the L2-hot W loads freely). x is
// L3-resident so the rz=1 duplicate read is cheap.
// Outputs byte-identical: q fp16 [b][n][64] (log2e), k/v fragment layouts.
// ---------------------------------------------------------------------------
__global__ __launch_bounds__(640, 2) void proj_kernel(
    const float* __restrict__ x,
    const float* __restrict__ Wq, const float* __restrict__ bq,
    const float* __restrict__ Wk, const float* __restrict__ bk,
    const float* __restrict__ Wv, const float* __restrict__ bv,
    u16* __restrict__ qh, u16* __restrict__ kh, u16* __restrict__ vv)
{
  const int b = blockIdx.y;
  const int rz = blockIdx.z;          // row-half: rows rz*320 .. rz*320+319
  const int nbase = blockIdx.x * 32;
  const int tid = threadIdx.x;
  const int w = tid >> 6;             // 10 waves; wave = 32 output rows
  const int lane = tid & 63;
  const int lhi = lane >> 5, llo = lane & 31;
  const int rowbase = rz * 320 + w * 32;

  __shared__ u16 xs[32 * 524 + 8];    // [n][k] fp16, row stride 524, 33.6 KB

  const float* xb = x + (size_t)b * CDIM * NPIX + nbase;

  // Stage x tile [512 k][32 n] -> fp16 transposed [n][k].
  if (tid < 512) {
    int r = tid >> 3;            // 0..63
    int ci = (tid & 7) << 2;     // 0..28
#pragma unroll
    for (int it = 0; it < 8; ++it) {
      int krow = it * 64 + r;
      f32x4 v4 = *(const f32x4*)&xb[(size_t)krow * NPIX + ci];
#pragma unroll
      for (int d = 0; d < 4; ++d) xs[(ci + d) * 524 + krow] = f2h(v4[d]);
    }
  }

  const int row = rowbase + llo;
  const float* wrow = (row < 64) ? (Wq + (size_t)row * CDIM)
                    : (row < 128) ? (Wk + (size_t)(row - 64) * CDIM)
                                  : (Wv + (size_t)(row - 128) * CDIM);

  f32x16 acc = zero16();
  __syncthreads();   // xs ready; no further barriers

  const char* xrow = (const char*)xs + llo * 1048 + 16 * lhi;
#pragma unroll 4
  for (int ks = 0; ks < 32; ++ks) {
    const float* wp = wrow + ks * 16 + 8 * lhi;
    f32x4 w0 = *(const f32x4*)(wp);
    f32x4 w1 = *(const f32x4*)(wp + 4);
    half8 af;
#pragma unroll
    for (int j = 0; j < 4; ++j) {
      af[j] = (_Float16)w0[j];
      af[4 + j] = (_Float16)w1[j];
    }
    half4 x0 = *(const half4*)(xrow + ks * 32);
    half4 x1 = *(const half4*)(xrow + ks * 32 + 8);
    acc = mfma_h32(af, h8(x0, x1), acc);
  }

  // Epilogue: C/D col = lane&31 (n), row = (r&3)+8*(r>>2)+4*lhi.
  // Wave-uniform type: rowbase>>5 in {0,1}: q; {2,3}: k; else v.
  const int type = rowbase >> 5;
  const int n = nbase + llo;
  if (type < 2) {       // q: fp16, log2e-scaled, [b][n][64]
#pragma unroll
    for (int gq = 0; gq < 4; ++gq) {
      int dr0 = 8 * gq + 4 * lhi;
      u16x4 hq;
#pragma unroll
      for (int jj = 0; jj < 4; ++jj) {
        float v = acc[4 * gq + jj] + bq[rowbase + dr0 + jj];
        hq[jj] = f2h(v * LOG2E);
      }
      *(u16x4*)(qh + ((size_t)b * NPIX + n) * 64 + rowbase + dr0) = hq;
    }
  } else if (type < 4) {  // k: fp16, fragment layout
    const int base = rowbase - 64;  // 0 or 32
    const int T = n >> 7, kq = (n >> 5) & 3, lf = n & 31;
#pragma unroll
    for (int gq = 0; gq < 4; ++gq) {
      int dr0 = 8 * gq + 4 * lhi;
      u16x4 hk;
#pragma unroll
      for (int jj = 0; jj < 4; ++jj)
        hk[jj] = f2h(acc[4 * gq + jj] + bk[base + dr0 + jj]);
      int sf = (base >> 4) + (gq >> 1);
      int lh = ((base >> 3) + gq) & 1;
      size_t F = (((size_t)b * 32 + T) * 4 + kq) * 4 + sf;
      *(u16x4*)(kh + F * 512 + (32 * lh + lf) * 8 + 4 * lhi) = hk;
    }
  } else {              // v: bf16, fragment layout
    const int T = n >> 7, s = (n >> 4) & 7, lh = (n >> 3) & 1, jn = n & 7;
#pragma unroll
    for (int gq = 0; gq < 4; ++gq) {
      int dr0 = 8 * gq + 4 * lhi;
#pragma unroll
      for (int jj = 0; jj < 4; ++jj) {
        int c = rowbase - 128 + dr0 + jj;
        float v = acc[4 * gq + jj] + bv[c];
        size_t F = ((((size_t)b * 2 + (c >> 8)) * 8 + ((c >> 5) & 7)) * 32 + T) * 8 + s;
        vv[F * 512 + (32 * lh + (c & 31)) * 8 + jn] = f2bf(v);
      }
    }
  }
}

// ---------------------------------------------------------------------------
// Kernel 2: attention — R20's validated structure; ONE change: P row stride
// 128 -> 136 B, XOR swizzle removed, reads as ds_read_b64 pairs. Bank math:
// lane llo's row base llo*136 -> bank llo*34 mod 32 = llo*2 mod 32 -> 16
// banks, 2 lanes/bank = free (m136). No XOR -> offsets are immediates, one
// address register (avoids R17's temp-spill failure mode). S scalar writes
// stay ~2-way. Everything else byte-identical to R20.
// ---------------------------------------------------------------------------

#define LOADK(T) do {                                                         \
  size_t F_ = (((size_t)batch * 32 + ((T) >> 1)) * 4                          \
               + (2 * ((T) & 1) + kq)) * 4;                                   \
  const u16* kp_ = kh + F_ * 512 + (size_t)lane * 8;                          \
  _Pragma("unroll") for (int s_ = 0; s_ < 4; ++s_)                            \
    kf[s_] = *(const half8*)(kp_ + s_ * 512);                                 \
} while (0)

#define S_PHASE(PB) do {                                                      \
  f32x16 sacc_ = zero16();                                                    \
  _Pragma("unroll") for (int s_ = 0; s_ < 4; ++s_) {                          \
    half8 qf_ = *(const half8*)(Qs + (2 * s_ + lhi) * 1024                    \
                                + (32 * rb_s + llo) * 16);                    \
    sacc_ = mfma_h32(qf_, kf[s_], sacc_);                                     \
  }                                                                           \
  _Pragma("unroll") for (int r_ = 0; r_ < 16; ++r_) {                         \
    float p_ = __builtin_amdgcn_exp2f(sacc_[r_]);                             \
    u16 pb_ = f2bf(p_);                                                       \
    l_part[r_] += bf2f(pb_);                                                  \
    int row_ = 32 * rb_s + (r_ & 3) + 8 * (r_ >> 2) + 4 * lhi;                \
    *(u16*)((PB) + row_ * 136 + (32 * kq + llo) * 2) = pb_;                   \
  }                                                                           \
} while (0)

// V fragments for 64-key tile T, wave w's 32 channels: 4 x b128, coalesced.
#define PVLOADV(T) do {                                                       \
  size_t F0_ = (size_t)(bc8 + w) * 256                                        \
               + (size_t)(((T) >> 1) * 8 + 4 * ((T) & 1));                    \
  const u16* g_ = vv + F0_ * 512 + (size_t)lane * 8;                          \
  vf[0] = *(const bf16x8*)(g_);                                               \
  vf[1] = *(const bf16x8*)(g_ + 512);                                         \
  vf[2] = *(const bf16x8*)(g_ + 1024);                                        \
  vf[3] = *(const bf16x8*)(g_ + 1536);                                        \
} while (0)

// PV: P reads as b64 pairs from the 136B-stride buffer; setprio around MFMAs.
#define PV_PHASE(PB) do {                                                     \
  const char* pr_ = (PB) + llo * 136 + 16 * lhi;                              \
  __builtin_amdgcn_s_setprio(1);                                              \
  _Pragma("unroll") for (int s_ = 0; s_ < 4; ++s_) {                          \
    bf16x4 a0_ = *(const bf16x4*)(pr_ + 32 * s_);                             \
    bf16x4 a1_ = *(const bf16x4*)(pr_ + 32 * s_ + 8);                         \
    bf16x4 c0_ = *(const bf16x4*)(pr_ + 4352 + 32 * s_);                      \
    bf16x4 c1_ = *(const bf16x4*)(pr_ + 4352 + 32 * s_ + 8);                  \
    acc0 = mfma_bf(b8(a0_, a1_), vf[s_], acc0);                               \
    acc1 = mfma_bf(b8(c0_, c1_), vf[s_], acc1);                               \
  }                                                                           \
  __builtin_amdgcn_s_setprio(0);                                              \
} while (0)

__global__ __launch_bounds__(1024) void attn_kernel(
    const u16* __restrict__ qh, const u16* __restrict__ kh,
    const u16* __restrict__ vv,
    const float* __restrict__ x, const float* __restrict__ gamma,
    float* __restrict__ out)
{
  const int bid = blockIdx.x;
  const int sw = ((bid & 7) << 6) | (bid >> 3);  // bijective, 512 = 8*64
  const int batch = sw >> 7;
  const int chhalf = (sw >> 6) & 1;
  const int qbase = (sw & 63) * 64;
  const int tid = threadIdx.x;
  const int w = tid >> 6;             // 0-7 PV; 8-11 S grp0; 12-15 S grp1
  const int lane = tid & 63;
  const int lhi = lane >> 5, llo = lane & 31;
  const bool isPV = (w < 8);
  const int grp = (w >= 12) ? 1 : 0;
  const int swv = (w - 8) & 3;
  const int rb_s = swv & 1;           // S row half (q 0-31 / 32-63)
  const int kq = swv >> 1;            // S key block (0..1) in 64-key tile
  const int bc8 = (batch * 2 + chhalf) * 8;

  __shared__ alignas(16) char Psm[17408];   // 2 x [64 rows x 136 B] bf16
  __shared__ alignas(16) char Qs[8192];     // [d8][64 q] x 16 B, slot-major
  __shared__ float lred[64][4];
  __shared__ alignas(16) float rl_lds[64];

  f32x16 acc0 = zero16(), acc1 = zero16();
  float l_part[16];
#pragma unroll
  for (int r = 0; r < 16; ++r) l_part[r] = 0.0f;
  half8 kf[4];
  bf16x8 vf[4];

  // Prologue A: grp0 fills Qs + LOADK(0); grp1 LOADK(2).
  if (!isPV) {
    if (grp == 0) {
#pragma unroll
      for (int j = 0; j < 2; ++j) {
        int idx = swv * 128 + j * 64 + lane;   // 0..511
        int d8 = idx & 7, row = idx >> 3;
        *(u16x8*)(Qs + d8 * 1024 + row * 16) =
            *(const u16x8*)(qh + ((size_t)batch * NPIX + qbase + row) * 64 + d8 * 8);
      }
      LOADK(0);
    } else {
      LOADK(2);
    }
  }
  __syncthreads();
  // Prologue B: grp0 builds tile 0 -> P[0] (kf = K(0)), then LOADK(1).
  if (!isPV && grp == 0) { S_PHASE(Psm); LOADK(1); }
  __syncthreads();

  // Main loop: phase t: PV loads V(t) (issue-early) then consumes P[t&1];
  // S group (t&1) builds tile t+1 into P[(t+1)&1] (kf = K(t+1), loaded two
  // phases earlier), then issues LOADK(t+3).
  for (int t = 0; t < 64; ++t) {
    if (isPV) {
      PVLOADV(t);
      PV_PHASE(Psm + (t & 1) * 8704);
    } else if (grp == (t & 1)) {
      if (t + 1 < 64) {
        S_PHASE(Psm + ((t + 1) & 1) * 8704);
        if (t + 3 < 64) LOADK(t + 3);
      }
    }
    __syncthreads();
  }

  // l reduction: butterfly over 32 key-lanes; 2 kq x 2 grp partials per row.
  if (!isPV) {
#pragma unroll
    for (int d = 1; d < 32; d <<= 1)
#pragma unroll
      for (int r = 0; r < 16; ++r) l_part[r] += __shfl_xor(l_part[r], d, 64);
    if (llo == 0) {
#pragma unroll
      for (int r = 0; r < 16; ++r) {
        int row = 32 * rb_s + (r & 3) + 8 * (r >> 2) + 4 * lhi;
        lred[row][2 * kq + grp] = l_part[r];
      }
    }
  }
  __syncthreads();
  if (tid < 64)
    rl_lds[tid] = 1.0f / (lred[tid][0] + lred[tid][1] + lred[tid][2] + lred[tid][3]);
  __syncthreads();

  // Epilogue (PV waves): out = gamma * acc/l + x.
  if (isPV) {
    const float g = gamma[0];
    const int c = chhalf * 256 + 32 * w + llo;
#pragma unroll
    for (int ab = 0; ab < 2; ++ab) {
      const f32x16& a = ab ? acc1 : acc0;
#pragma unroll
      for (int gq = 0; gq < 4; ++gq) {
        int qrow = 32 * ab + 8 * gq + 4 * lhi;
        size_t off = ((size_t)batch * CDIM + c) * NPIX + qbase + qrow;
        f32x4 xv = *(const f32x4*)(x + off);
        f32x4 rlv = *(const f32x4*)&rl_lds[qrow];
        f32x4 ov;
#pragma unroll
        for (int jj = 0; jj < 4; ++jj)
          ov[jj] = g * a[4 * gq + jj] * rlv[jj] + xv[jj];
        *(f32x4*)(out + off) = ov;
      }
    }
  }
}

extern "C" void kernel_launch(void* const* d_in, const int* in_sizes, int n_in,
                              void* d_out, int out_size, void* d_ws, size_t ws_size,
                              hipStream_t stream) {
  (void)in_sizes; (void)n_in; (void)out_size; (void)ws_size;
  const float* x     = (const float*)d_in[0];
  const float* Wq    = (const float*)d_in[1];
  const float* bq    = (const float*)d_in[2];
  const float* Wk    = (const float*)d_in[3];
  const float* bk    = (const float*)d_in[4];
  const float* Wv    = (const float*)d_in[5];
  const float* bv    = (const float*)d_in[6];
  const float* gamma = (const float*)d_in[7];
  float* out = (float*)d_out;

  // Workspace layout (bytes): q fp16 0..2M, k-frag fp16 2..4M, v-frag bf16 4..20M.
  char* ws = (char*)d_ws;
  u16* qh = (u16*)(ws);
  u16* kh = (u16*)(ws + (2u << 20));
  u16* vv = (u16*)(ws + (4u << 20));

  proj_kernel<<<dim3(128, 4, 2), 640, 0, stream>>>(x, Wq, bq, Wk, bk, Wv, bv,
                                                   qh, kh, vv);
  attn_kernel<<<512, 1024, 0, stream>>>(qh, kh, vv, x, gamma, out);
}

// Round 22
// 173.597 us; speedup vs baseline: 1.1850x; 1.1850x over previous
//
#include <hip/hip_runtime.h>
#include <hip/hip_bf16.h>

typedef unsigned short u16;
typedef float f32x4 __attribute__((ext_vector_type(4)));
typedef float f32x16 __attribute__((ext_vector_type(16)));
typedef __bf16 bf16x4 __attribute__((ext_vector_type(4)));
typedef __bf16 bf16x8 __attribute__((ext_vector_type(8)));
typedef _Float16 half4 __attribute__((ext_vector_type(4)));
typedef _Float16 half8 __attribute__((ext_vector_type(8)));
typedef u16 u16x4 __attribute__((ext_vector_type(4)));
typedef u16 u16x8 __attribute__((ext_vector_type(8)));

#define NPIX 4096
#define CDIM 512
#define LOG2E 1.4426950408889634f

static __device__ __forceinline__ u16 f2bf(float f) {
  return __builtin_bit_cast(u16, (__bf16)f);
}
static __device__ __forceinline__ float bf2f(u16 u) {
  unsigned int v = ((unsigned int)u) << 16;
  return __builtin_bit_cast(float, v);
}
static __device__ __forceinline__ u16 f2h(float f) {
  return __builtin_bit_cast(u16, (_Float16)f);
}
static __device__ __forceinline__ f32x16 zero16() {
  f32x16 z;
#pragma unroll
  for (int i = 0; i < 16; ++i) z[i] = 0.0f;
  return z;
}
static __device__ __forceinline__ f32x16 mfma_bf(bf16x8 a, bf16x8 b, f32x16 c) {
  return __builtin_amdgcn_mfma_f32_32x32x16_bf16(a, b, c, 0, 0, 0);
}
static __device__ __forceinline__ f32x16 mfma_h32(half8 a, half8 b, f32x16 c) {
  return __builtin_amdgcn_mfma_f32_32x32x16_f16(a, b, c, 0, 0, 0);
}
static __device__ __forceinline__ half8 h8(half4 a, half4 b) {
  half8 r;
#pragma unroll
  for (int i = 0; i < 4; ++i) { r[i] = a[i]; r[4 + i] = b[i]; }
  return r;
}
static __device__ __forceinline__ bf16x8 b8(bf16x4 a, bf16x4 b) {
  bf16x8 r;
#pragma unroll
  for (int i = 0; i < 4; ++i) { r[i] = a[i]; r[4 + i] = b[i]; }
  return r;
}

// ---------------------------------------------------------------------------
// Kernel 1: fused QKV projection. R21 post-mortem: the 64-VGPR shape was
// right (no spills) but 32-wide n-tiles made 1024 blocks stream W = 1.25 GB
// from L2/L3. R22: 64-wide n-tiles (512 blocks, W traffic /4 = 320 MB) while
// keeping the spill-free wave shape: wave owns 32 rows x 64 n -> acc[2] =
// 32 regs (~60 total). x staged fp16 in TWO k-halves ([64n][260k] = 33 KB,
// stride-260 -> ~2-way reads), 3 barriers; MFMA loop otherwise barrier-free.
// Outputs byte-identical: q fp16 [b][n][64] (log2e), k/v fragment layouts.
// ---------------------------------------------------------------------------
__global__ __launch_bounds__(640, 2) void proj_kernel(
    const float* __restrict__ x,
    const float* __restrict__ Wq, const float* __restrict__ bq,
    const float* __restrict__ Wk, const float* __restrict__ bk,
    const float* __restrict__ Wv, const float* __restrict__ bv,
    u16* __restrict__ qh, u16* __restrict__ kh, u16* __restrict__ vv)
{
  const int b = blockIdx.y;
  const int rz = blockIdx.z;          // row-half: rows rz*320 .. rz*320+319
  const int nbase = blockIdx.x * 64;
  const int tid = threadIdx.x;
  const int w = tid >> 6;             // 10 waves; wave = 32 output rows
  const int lane = tid & 63;
  const int lhi = lane >> 5, llo = lane & 31;
  const int rowbase = rz * 320 + w * 32;

  __shared__ u16 xs[64 * 260];        // [n][k-half] fp16, stride 260, 33.3 KB

  const float* xb = x + (size_t)b * CDIM * NPIX + nbase;

  const int row = rowbase + llo;
  const float* wrow = (row < 64) ? (Wq + (size_t)row * CDIM)
                    : (row < 128) ? (Wk + (size_t)(row - 64) * CDIM)
                                  : (Wv + (size_t)(row - 128) * CDIM);

  f32x16 acc0 = zero16(), acc1 = zero16();

  for (int kh2 = 0; kh2 < 2; ++kh2) {
    __syncthreads();   // previous half's consumers done; xs free
    if (tid < 512) {
      int r = tid >> 4;            // 0..31
      int ci = (tid & 15) << 2;    // 0..60
#pragma unroll
      for (int it = 0; it < 8; ++it) {
        int krow = it * 32 + r;    // 0..255 within half
        f32x4 v4 = *(const f32x4*)&xb[(size_t)(kh2 * 256 + krow) * NPIX + ci];
#pragma unroll
        for (int d = 0; d < 4; ++d) xs[(ci + d) * 260 + krow] = f2h(v4[d]);
      }
    }
    __syncthreads();   // xs ready

#pragma unroll 4
    for (int ks = 0; ks < 16; ++ks) {
      const float* wp = wrow + kh2 * 256 + ks * 16 + 8 * lhi;
      f32x4 w0 = *(const f32x4*)(wp);
      f32x4 w1 = *(const f32x4*)(wp + 4);
      half8 af;
#pragma unroll
      for (int j = 0; j < 4; ++j) {
        af[j] = (_Float16)w0[j];
        af[4 + j] = (_Float16)w1[j];
      }
      const char* xk = (const char*)xs + (ks * 16 + 8 * lhi) * 2;
      half4 x00 = *(const half4*)(xk + (size_t)llo * 520);
      half4 x01 = *(const half4*)(xk + (size_t)llo * 520 + 8);
      half4 x10 = *(const half4*)(xk + (size_t)(32 + llo) * 520);
      half4 x11 = *(const half4*)(xk + (size_t)(32 + llo) * 520 + 8);
      acc0 = mfma_h32(af, h8(x00, x01), acc0);
      acc1 = mfma_h32(af, h8(x10, x11), acc1);
    }
  }

  // Epilogue: C/D col = lane&31 (n within 32-block), row = (r&3)+8*(r>>2)+4*lhi.
  const int type = rowbase >> 5;   // {0,1}: q; {2,3}: k; else v
#pragma unroll
  for (int cb = 0; cb < 2; ++cb) {
    const f32x16& acc = cb ? acc1 : acc0;
    const int n = nbase + 32 * cb + llo;
    if (type < 2) {       // q: fp16, log2e-scaled, [b][n][64]
#pragma unroll
      for (int gq = 0; gq < 4; ++gq) {
        int dr0 = 8 * gq + 4 * lhi;
        u16x4 hq;
#pragma unroll
        for (int jj = 0; jj < 4; ++jj) {
          float v = acc[4 * gq + jj] + bq[rowbase + dr0 + jj];
          hq[jj] = f2h(v * LOG2E);
        }
        *(u16x4*)(qh + ((size_t)b * NPIX + n) * 64 + rowbase + dr0) = hq;
      }
    } else if (type < 4) {  // k: fp16, fragment layout
      const int base = rowbase - 64;  // 0 or 32
      const int T = n >> 7, kq = (n >> 5) & 3, lf = n & 31;
#pragma unroll
      for (int gq = 0; gq < 4; ++gq) {
        int dr0 = 8 * gq + 4 * lhi;
        u16x4 hk;
#pragma unroll
        for (int jj = 0; jj < 4; ++jj)
          hk[jj] = f2h(acc[4 * gq + jj] + bk[base + dr0 + jj]);
        int sf = (base >> 4) + (gq >> 1);
        int lh = gq & 1;
        size_t F = (((size_t)b * 32 + T) * 4 + kq) * 4 + sf;
        *(u16x4*)(kh + F * 512 + (32 * lh + lf) * 8 + 4 * lhi) = hk;
      }
    } else {              // v: bf16, fragment layout
      const int T = n >> 7, s = (n >> 4) & 7, lh = (n >> 3) & 1, jn = n & 7;
#pragma unroll
      for (int gq = 0; gq < 4; ++gq) {
        int dr0 = 8 * gq + 4 * lhi;
#pragma unroll
        for (int jj = 0; jj < 4; ++jj) {
          int c = rowbase - 128 + dr0 + jj;
          float v = acc[4 * gq + jj] + bv[c];
          size_t F = ((((size_t)b * 2 + (c >> 8)) * 8 + ((c >> 5) & 7)) * 32 + T) * 8 + s;
          vv[F * 512 + (32 * lh + (c & 31)) * 8 + jn] = f2bf(v);
        }
      }
    }
  }
}

// ---------------------------------------------------------------------------
// Kernel 2: attention — byte-identical to R21 (132 µs, conflicts 229K).
// ---------------------------------------------------------------------------

#define LOADK(T) do {                                                         \
  size_t F_ = (((size_t)batch * 32 + ((T) >> 1)) * 4                          \
               + (2 * ((T) & 1) + kq)) * 4;                                   \
  const u16* kp_ = kh + F_ * 512 + (size_t)lane * 8;                          \
  _Pragma("unroll") for (int s_ = 0; s_ < 4; ++s_)                            \
    kf[s_] = *(const half8*)(kp_ + s_ * 512);                                 \
} while (0)

#define S_PHASE(PB) do {                                                      \
  f32x16 sacc_ = zero16();                                                    \
  _Pragma("unroll") for (int s_ = 0; s_ < 4; ++s_) {                          \
    half8 qf_ = *(const half8*)(Qs + (2 * s_ + lhi) * 1024                    \
                                + (32 * rb_s + llo) * 16);                    \
    sacc_ = mfma_h32(qf_, kf[s_], sacc_);                                     \
  }                                                                           \
  _Pragma("unroll") for (int r_ = 0; r_ < 16; ++r_) {                         \
    float p_ = __builtin_amdgcn_exp2f(sacc_[r_]);                             \
    u16 pb_ = f2bf(p_);                                                       \
    l_part[r_] += bf2f(pb_);                                                  \
    int row_ = 32 * rb_s + (r_ & 3) + 8 * (r_ >> 2) + 4 * lhi;                \
    *(u16*)((PB) + row_ * 136 + (32 * kq + llo) * 2) = pb_;                   \
  }                                                                           \
} while (0)

#define PVLOADV(T) do {                                                       \
  size_t F0_ = (size_t)(bc8 + w) * 256                                        \
               + (size_t)(((T) >> 1) * 8 + 4 * ((T) & 1));                    \
  const u16* g_ = vv + F0_ * 512 + (size_t)lane * 8;                          \
  vf[0] = *(const bf16x8*)(g_);                                               \
  vf[1] = *(const bf16x8*)(g_ + 512);                                         \
  vf[2] = *(const bf16x8*)(g_ + 1024);                                        \
  vf[3] = *(const bf16x8*)(g_ + 1536);                                        \
} while (0)

#define PV_PHASE(PB) do {                                                     \
  const char* pr_ = (PB) + llo * 136 + 16 * lhi;                              \
  __builtin_amdgcn_s_setprio(1);                                              \
  _Pragma("unroll") for (int s_ = 0; s_ < 4; ++s_) {                          \
    bf16x4 a0_ = *(const bf16x4*)(pr_ + 32 * s_);                             \
    bf16x4 a1_ = *(const bf16x4*)(pr_ + 32 * s_ + 8);                         \
    bf16x4 c0_ = *(const bf16x4*)(pr_ + 4352 + 32 * s_);                      \
    bf16x4 c1_ = *(const bf16x4*)(pr_ + 4352 + 32 * s_ + 8);                  \
    acc0 = mfma_bf(b8(a0_, a1_), vf[s_], acc0);                               \
    acc1 = mfma_bf(b8(c0_, c1_), vf[s_], acc1);                               \
  }                                                                           \
  __builtin_amdgcn_s_setprio(0);                                              \
} while (0)

__global__ __launch_bounds__(1024) void attn_kernel(
    const u16* __restrict__ qh, const u16* __restrict__ kh,
    const u16* __restrict__ vv,
    const float* __restrict__ x, const float* __restrict__ gamma,
    float* __restrict__ out)
{
  const int bid = blockIdx.x;
  const int sw = ((bid & 7) << 6) | (bid >> 3);  // bijective, 512 = 8*64
  const int batch = sw >> 7;
  const int chhalf = (sw >> 6) & 1;
  const int qbase = (sw & 63) * 64;
  const int tid = threadIdx.x;
  const int w = tid >> 6;             // 0-7 PV; 8-11 S grp0; 12-15 S grp1
  const int lane = tid & 63;
  const int lhi = lane >> 5, llo = lane & 31;
  const bool isPV = (w < 8);
  const int grp = (w >= 12) ? 1 : 0;
  const int swv = (w - 8) & 3;
  const int rb_s = swv & 1;           // S row half (q 0-31 / 32-63)
  const int kq = swv >> 1;            // S key block (0..1) in 64-key tile
  const int bc8 = (batch * 2 + chhalf) * 8;

  __shared__ alignas(16) char Psm[17408];   // 2 x [64 rows x 136 B] bf16
  __shared__ alignas(16) char Qs[8192];     // [d8][64 q] x 16 B, slot-major
  __shared__ float lred[64][4];
  __shared__ alignas(16) float rl_lds[64];

  f32x16 acc0 = zero16(), acc1 = zero16();
  float l_part[16];
#pragma unroll
  for (int r = 0; r < 16; ++r) l_part[r] = 0.0f;
  half8 kf[4];
  bf16x8 vf[4];

  // Prologue A: grp0 fills Qs + LOADK(0); grp1 LOADK(2).
  if (!isPV) {
    if (grp == 0) {
#pragma unroll
      for (int j = 0; j < 2; ++j) {
        int idx = swv * 128 + j * 64 + lane;   // 0..511
        int d8 = idx & 7, row = idx >> 3;
        *(u16x8*)(Qs + d8 * 1024 + row * 16) =
            *(const u16x8*)(qh + ((size_t)batch * NPIX + qbase + row) * 64 + d8 * 8);
      }
      LOADK(0);
    } else {
      LOADK(2);
    }
  }
  __syncthreads();
  // Prologue B: grp0 builds tile 0 -> P[0] (kf = K(0)), then LOADK(1).
  if (!isPV && grp == 0) { S_PHASE(Psm); LOADK(1); }
  __syncthreads();

  // Main loop: phase t: PV loads V(t) (issue-early) then consumes P[t&1];
  // S group (t&1) builds tile t+1 into P[(t+1)&1], then issues LOADK(t+3).
  for (int t = 0; t < 64; ++t) {
    if (isPV) {
      PVLOADV(t);
      PV_PHASE(Psm + (t & 1) * 8704);
    } else if (grp == (t & 1)) {
      if (t + 1 < 64) {
        S_PHASE(Psm + ((t + 1) & 1) * 8704);
        if (t + 3 < 64) LOADK(t + 3);
      }
    }
    __syncthreads();
  }

  // l reduction: butterfly over 32 key-lanes; 2 kq x 2 grp partials per row.
  if (!isPV) {
#pragma unroll
    for (int d = 1; d < 32; d <<= 1)
#pragma unroll
      for (int r = 0; r < 16; ++r) l_part[r] += __shfl_xor(l_part[r], d, 64);
    if (llo == 0) {
#pragma unroll
      for (int r = 0; r < 16; ++r) {
        int row = 32 * rb_s + (r & 3) + 8 * (r >> 2) + 4 * lhi;
        lred[row][2 * kq + grp] = l_part[r];
      }
    }
  }
  __syncthreads();
  if (tid < 64)
    rl_lds[tid] = 1.0f / (lred[tid][0] + lred[tid][1] + lred[tid][2] + lred[tid][3]);
  __syncthreads();

  // Epilogue (PV waves): out = gamma * acc/l + x.
  if (isPV) {
    const float g = gamma[0];
    const int c = chhalf * 256 + 32 * w + llo;
#pragma unroll
    for (int ab = 0; ab < 2; ++ab) {
      const f32x16& a = ab ? acc1 : acc0;
#pragma unroll
      for (int gq = 0; gq < 4; ++gq) {
        int qrow = 32 * ab + 8 * gq + 4 * lhi;
        size_t off = ((size_t)batch * CDIM + c) * NPIX + qbase + qrow;
        f32x4 xv = *(const f32x4*)(x + off);
        f32x4 rlv = *(const f32x4*)&rl_lds[qrow];
        f32x4 ov;
#pragma unroll
        for (int jj = 0; jj < 4; ++jj)
          ov[jj] = g * a[4 * gq + jj] * rlv[jj] + xv[jj];
        *(f32x4*)(out + off) = ov;
      }
    }
  }
}

extern "C" void kernel_launch(void* const* d_in, const int* in_sizes, int n_in,
                              void* d_out, int out_size, void* d_ws, size_t ws_size,
                              hipStream_t stream) {
  (void)in_sizes; (void)n_in; (void)out_size; (void)ws_size;
  const float* x     = (const float*)d_in[0];
  const float* Wq    = (const float*)d_in[1];
  const float* bq    = (const float*)d_in[2];
  const float* Wk    = (const float*)d_in[3];
  const float* bk    = (const float*)d_in[4];
  const float* Wv    = (const float*)d_in[5];
  const float* bv    = (const float*)d_in[6];
  const float* gamma = (const float*)d_in[7];
  float* out = (float*)d_out;

  // Workspace layout (bytes): q fp16 0..2M, k-frag fp16 2..4M, v-frag bf16 4..20M.
  char* ws = (char*)d_ws;
  u16* qh = (u16*)(ws);
  u16* kh = (u16*)(ws + (2u << 20));
  u16* vv = (u16*)(ws + (4u << 20));

  proj_kernel<<<dim3(64, 4, 2), 640, 0, stream>>>(x, Wq, bq, Wk, bk, Wv, bv,
                                                  qh, kh, vv);
  attn_kernel<<<512, 1024, 0, stream>>>(qh, kh, vv, x, gamma, out);
}